// Round 12
// baseline (2974.955 us; speedup 1.0000x reference)
//
#include <hip/hip_runtime.h>
#include <math.h>

// MeshSDFLoss: P=16384 points vs F=16384 triangles, min sqdist + argmin + loss.
// Outputs (flat float32): [0]=loss, [1..P]=dist, [1+P..1+2P]=assoc (as float).
//
// R12: three-phase decoupled pipeline.
//  Phase 0 (seed): 32 exact execs/point from the Morton face window ->
//    best[p] (packed u64) and hint[p] (sqrt dist) via plain stores.
//  Phase 1 (scan+emit): fixed thr = hint*1.005+1e-3. Plane-band scan (R7 kp
//    certificate, wave-uniform loads) -> 64-bit mask; AABB+J filter (R11
//    certificate) on mask bits; survivors emitted to a global worklist
//    (wave-aggregated atomicAdd). Overflow -> inline exec (correctness never
//    depends on list capacity).
//  Phase 2 (exec): one lane per (pid,fi) candidate, bit-exact exec_pair,
//    atomicMin(best[pid]).
//  Certificates: skip => ref_d > thr >= sqrt(final_best)*1.005+1e-3 => the
//  skipped face can never be or tie the argmin. Exempt faces (noise-dominated
//  denominators): kp band=1e30 and J=1e30 -> always emitted/executed.
//  Tie-break: packed (distbits<<32)|origIdx u64 min == np.argmin first-index.

#define PTOT 16384
#define FTOT 16384
#define NBINS 4096
#define BLOCK 256
#define NCH 32
#define FCHUNK (FTOT / NCH)   // 512 faces per chunk, 8 windows of 64

// ws layout (bytes)
#define WS_BEST    0           // u64[16384]            -> 131072
#define WS_SORTP   131072      // uint4[16384]          -> 393216
#define WS_HISTP   393216      // u32[4096]             -> 409600   (zeroed)
#define WS_HISTF   409600      // u32[4096]             -> 425984   (zeroed)
#define WS_LISTCNT 425984      // u32 (+pad)            -> 426240   (zeroed)
#define WS_HISTFC  426240      // u32[4096]             -> 442624
#define WS_HINT    442624      // u32[16384]            -> 508160
#define WS_FA      508160      // float4[16384] {a, origIdxBits}
#define WS_FB      770304      // float4[16384]
#define WS_FC      1032448     // float4[16384]
#define WS_FSCAN   1294592     // float4[16384] {nh, md0}
#define WS_FBAND   1556736     // float[16384]  {kp band}
#define WS_FBOXC   1622272     // float4[16384] {box center, hx}
#define WS_FBOXH   1884416     // float4[16384] {hy, hz, J, 0}
#define WS_LIST    2146560     // u32[CAP] worklist (pid<<16|fi)
#define ZERO_BYTES (16384 + 16384 + 256)   // histP + histF + listCnt

__device__ __forceinline__ unsigned morton12(float x, float y, float z) {
    int ix = (int)(x * 16.0f); ix = ix < 0 ? 0 : (ix > 15 ? 15 : ix);
    int iy = (int)(y * 16.0f); iy = iy < 0 ? 0 : (iy > 15 ? 15 : iy);
    int iz = (int)(z * 16.0f); iz = iz < 0 ? 0 : (iz > 15 ? 15 : iz);
    unsigned code = 0;
#pragma unroll
    for (int k = 0; k < 4; ++k) {
        code |= (((unsigned)(ix >> k) & 1u) << (3 * k + 2))
              | (((unsigned)(iy >> k) & 1u) << (3 * k + 1))
              | (((unsigned)(iz >> k) & 1u) << (3 * k + 0));
    }
    return code;
}

// Bit-exact point-triangle squared distance (reference-identical rounding).
__device__ __forceinline__ float exec_pair(
    float px, float py, float pz,
    float ax, float ay, float az,
    float bx, float by, float bz,
    float cx, float cy, float cz)
{
#pragma clang fp contract(off)
    const float abx = __fsub_rn(bx, ax), aby = __fsub_rn(by, ay), abz = __fsub_rn(bz, az);
    const float acx = __fsub_rn(cx, ax), acy = __fsub_rn(cy, ay), acz = __fsub_rn(cz, az);
    const float cbx = __fsub_rn(cx, bx), cby = __fsub_rn(cy, by), cbz = __fsub_rn(cz, bz);

    const float apx = __fsub_rn(px, ax), apy = __fsub_rn(py, ay), apz = __fsub_rn(pz, az);
    const float d1 = __fadd_rn(__fadd_rn(__fmul_rn(abx, apx), __fmul_rn(aby, apy)), __fmul_rn(abz, apz));
    const float d2 = __fadd_rn(__fadd_rn(__fmul_rn(acx, apx), __fmul_rn(acy, apy)), __fmul_rn(acz, apz));
    const float bpx = __fsub_rn(px, bx), bpy = __fsub_rn(py, by), bpz = __fsub_rn(pz, bz);
    const float d3 = __fadd_rn(__fadd_rn(__fmul_rn(abx, bpx), __fmul_rn(aby, bpy)), __fmul_rn(abz, bpz));
    const float d4 = __fadd_rn(__fadd_rn(__fmul_rn(acx, bpx), __fmul_rn(acy, bpy)), __fmul_rn(acz, bpz));
    const float cpx = __fsub_rn(px, cx), cpy = __fsub_rn(py, cy), cpz = __fsub_rn(pz, cz);
    const float d5 = __fadd_rn(__fadd_rn(__fmul_rn(abx, cpx), __fmul_rn(aby, cpy)), __fmul_rn(abz, cpz));
    const float d6 = __fadd_rn(__fadd_rn(__fmul_rn(acx, cpx), __fmul_rn(acy, cpy)), __fmul_rn(acz, cpz));

    const float vc_ = __fsub_rn(__fmul_rn(d1, d4), __fmul_rn(d3, d2));
    const float vb_ = __fsub_rn(__fmul_rn(d5, d2), __fmul_rn(d1, d6));
    const float va_ = __fsub_rn(__fmul_rn(d3, d6), __fmul_rn(d5, d4));

    const float den_ab = __fsub_rn(d1, d3);
    const float den_ac = __fsub_rn(d2, d6);
    const float t43    = __fsub_rn(d4, d3);
    const float t56    = __fsub_rn(d5, d6);
    const float den_bc = __fadd_rn(t43, t56);
    const float den_in = __fadd_rn(__fadd_rn(va_, vb_), vc_);

    const bool f_a  = (d1 <= 0.0f) && (d2 <= 0.0f);
    const bool f_b  = (d3 >= 0.0f) && (d4 <= d3);
    const bool f_c  = (d6 >= 0.0f) && (d5 <= d6);
    const bool f_ab = (vc_ <= 0.0f) && (d1 >= 0.0f) && (d3 <= 0.0f);
    const bool f_ac = (vb_ <= 0.0f) && (d2 >= 0.0f) && (d6 <= 0.0f);
    const bool f_bc = (va_ <= 0.0f) && (t43 >= 0.0f) && (t56 >= 0.0f);
    const bool vert = f_a || f_b || f_c;
    const bool e_ab = f_ab && !vert;
    const bool e_ac = f_ac && !vert && !f_ab;
    const bool e_bc = f_bc && !vert && !f_ab && !f_ac;
    const bool inte = !vert && !f_ab && !f_ac && !f_bc;

    const float num  = e_ab ? d1 : (e_ac ? d2 : (e_bc ? t43 : 1.0f));
    const float denr = e_ab ? den_ab : (e_ac ? den_ac : (e_bc ? den_bc : den_in));
    const float den  = (denr != 0.0f) ? denr : 1.0f;
    const float t    = __fdiv_rn(num, den);

    const float v_in = __fmul_rn(vb_, t);
    const float w_in = __fmul_rn(vc_, t);

    const float s1 = vert ? 0.0f : (inte ? v_in : t);
    const float s2 = inte ? w_in : 0.0f;
    const bool  sel_b = (!f_a && f_b) || e_bc;
    const bool  sel_c = !f_a && !f_b && f_c;
    const float e1x = e_ac ? acx : (e_bc ? cbx : abx);
    const float e1y = e_ac ? acy : (e_bc ? cby : aby);
    const float e1z = e_ac ? acz : (e_bc ? cbz : abz);
    const float bsx = sel_b ? bx : (sel_c ? cx : ax);
    const float bsy = sel_b ? by : (sel_c ? cy : ay);
    const float bsz = sel_b ? bz : (sel_c ? cz : az);
    const float qx = __fadd_rn(__fadd_rn(bsx, __fmul_rn(e1x, s1)), __fmul_rn(acx, s2));
    const float qy = __fadd_rn(__fadd_rn(bsy, __fmul_rn(e1y, s1)), __fmul_rn(acy, s2));
    const float qz = __fadd_rn(__fadd_rn(bsz, __fmul_rn(e1z, s1)), __fmul_rn(acz, s2));

    const float dxx = __fsub_rn(px, qx), dyy = __fsub_rn(py, qy), dzz = __fsub_rn(pz, qz);
    return __fadd_rn(__fadd_rn(__fmul_rn(dxx, dxx), __fmul_rn(dyy, dyy)), __fmul_rn(dzz, dzz));
}

// ---- prep: histograms ----
__global__ __launch_bounds__(BLOCK) void hist_kernel(
    const float* __restrict__ verts, const int* __restrict__ faces,
    const float* __restrict__ points,
    unsigned* __restrict__ histP, unsigned* __restrict__ histF)
{
    const int b = blockIdx.x;
    if (b < 64) {
        const int p = b * BLOCK + threadIdx.x;
        atomicAdd(&histP[morton12(points[p*3], points[p*3+1], points[p*3+2])], 1u);
    } else {
        const int f = (b - 64) * BLOCK + threadIdx.x;
        const int i0 = faces[f*3+0], i1 = faces[f*3+1], i2 = faces[f*3+2];
        const float mx = (verts[i0*3+0] + verts[i1*3+0] + verts[i2*3+0]) * (1.0f/3.0f);
        const float my = (verts[i0*3+1] + verts[i1*3+1] + verts[i2*3+1]) * (1.0f/3.0f);
        const float mz = (verts[i0*3+2] + verts[i1*3+2] + verts[i2*3+2]) * (1.0f/3.0f);
        atomicAdd(&histF[morton12(mx, my, mz)], 1u);
    }
}

__global__ __launch_bounds__(256) void scan_kernel(
    unsigned* __restrict__ histP, unsigned* __restrict__ histF,
    unsigned* __restrict__ histFC)
{
    unsigned* h = (blockIdx.x == 0) ? histP : histF;
    __shared__ unsigned ps[256];
    const int t = threadIdx.x;
    unsigned local[16];
    unsigned run = 0;
#pragma unroll
    for (int i = 0; i < 16; ++i) { unsigned v = h[t*16+i]; local[i] = run; run += v; }
    ps[t] = run;
    __syncthreads();
    for (int off = 1; off < 256; off <<= 1) {
        unsigned v = (t >= off) ? ps[t - off] : 0u;
        __syncthreads();
        ps[t] += v;
        __syncthreads();
    }
    const unsigned base = (t == 0) ? 0u : ps[t-1];
#pragma unroll
    for (int i = 0; i < 16; ++i) {
        const unsigned off = base + local[i];
        h[t*16+i] = off;
        if (blockIdx.x == 1) histFC[t*16+i] = off;
    }
}

// ---- prep: scatter + build certified metadata (fp64) ----
__global__ __launch_bounds__(BLOCK) void scatter_build_kernel(
    const float* __restrict__ verts, const int* __restrict__ faces,
    const float* __restrict__ points,
    unsigned* __restrict__ histP, unsigned* __restrict__ histF,
    uint4* __restrict__ sortP,
    float4* __restrict__ fA, float4* __restrict__ fB, float4* __restrict__ fC,
    float4* __restrict__ fScan, float* __restrict__ fBand,
    float4* __restrict__ fBoxC, float4* __restrict__ fBoxH)
{
    const int b = blockIdx.x;
    if (b < 64) {
        const int p = b * BLOCK + threadIdx.x;
        const float x = points[p*3], y = points[p*3+1], z = points[p*3+2];
        const unsigned pos = atomicAdd(&histP[morton12(x, y, z)], 1u);
        sortP[pos] = make_uint4(__float_as_uint(x), __float_as_uint(y),
                                __float_as_uint(z), (unsigned)p);
        return;
    }
    const int f = (b - 64) * BLOCK + threadIdx.x;
    const int i0 = faces[f*3+0], i1 = faces[f*3+1], i2 = faces[f*3+2];
    const float ax = verts[i0*3+0], ay = verts[i0*3+1], az = verts[i0*3+2];
    const float bx = verts[i1*3+0], by = verts[i1*3+1], bz = verts[i1*3+2];
    const float cx = verts[i2*3+0], cy = verts[i2*3+1], cz = verts[i2*3+2];
    const float mx = (ax+bx+cx) * (1.0f/3.0f);
    const float my = (ay+by+cy) * (1.0f/3.0f);
    const float mz = (az+bz+cz) * (1.0f/3.0f);
    const unsigned pos = atomicAdd(&histF[morton12(mx, my, mz)], 1u);

    fA[pos] = make_float4(ax, ay, az, __uint_as_float((unsigned)f));
    fB[pos] = make_float4(bx, by, bz, 0.0f);
    fC[pos] = make_float4(cx, cy, cz, 0.0f);

    const double abx = (double)bx-ax, aby = (double)by-ay, abz = (double)bz-az;
    const double acx = (double)cx-ax, acy = (double)cy-ay, acz = (double)cz-az;
    const double cbx = (double)cx-bx, cby = (double)cy-by, cbz = (double)cz-bz;
    const double nx = aby*acz - abz*acy;
    const double ny = abz*acx - abx*acz;
    const double nz = abx*acy - aby*acx;
    const double nn = nx*nx + ny*ny + nz*nz;
    const double e1 = sqrt(abx*abx + aby*aby + abz*abz);
    const double e2 = sqrt(acx*acx + acy*acy + acz*acz);
    const double e3 = sqrt(cbx*cbx + cby*cby + cbz*cbz);
    const double maxe = fmax(e1, fmax(e2, e3));
    const double mine = fmin(e1, fmin(e2, e3));
    const double mine2 = mine * mine;
    const double maxe2 = maxe * maxe;
    const double maxe3 = maxe2 * maxe;

    const bool exempt = !(nn > 1e-5 * maxe2) || !(mine2 > 5e-6 * maxe);

    float4 sc;
    float band, J;
    if (!exempt) {
        const double rin = 1.0 / sqrt(nn);
        sc.x = (float)(nx * rin);
        sc.y = (float)(ny * rin);
        sc.z = (float)(nz * rin);
        sc.w = (float)(-(nx*rin*ax + ny*rin*ay + nz*rin*az));
        band = (float)fmin(1e4, 3e-5 * maxe3 / nn + 2e-5);
        J    = (float)fmin(1e4, 1.2 * (6e-5 * maxe3 / nn
                                     + 5e-5 * maxe2 / mine2
                                     + 2.6e-6 * maxe / mine
                                     + 3.2e-3));
    } else {
        sc = make_float4(0.0f, 0.0f, 0.0f, 0.0f);  // pd = 0 -> always in band
        band = 1e30f;
        J    = 1e30f;                               // never box-skipped
    }
    fScan[pos] = sc;
    fBand[pos] = band;

    const double mnx = fmin((double)ax, fmin((double)bx, (double)cx));
    const double mxx = fmax((double)ax, fmax((double)bx, (double)cx));
    const double mny = fmin((double)ay, fmin((double)by, (double)cy));
    const double mxy = fmax((double)ay, fmax((double)by, (double)cy));
    const double mnz = fmin((double)az, fmin((double)bz, (double)cz));
    const double mxz = fmax((double)az, fmax((double)bz, (double)cz));
    const float ccx = (float)((mnx + mxx) * 0.5);
    const float ccy = (float)((mny + mxy) * 0.5);
    const float ccz = (float)((mnz + mxz) * 0.5);
    const float hx = (float)((mxx - mnx) * 0.5 * 1.0002 + 2e-5);
    const float hy = (float)((mxy - mny) * 0.5 * 1.0002 + 2e-5);
    const float hz = (float)((mxz - mnz) * 0.5 * 1.0002 + 2e-5);
    fBoxC[pos] = make_float4(ccx, ccy, ccz, hx);
    fBoxH[pos] = make_float4(hy, hz, J, 0.0f);
}

// ---- phase 0: 32 exact seeds/point, plain-store best+hint ----
__global__ __launch_bounds__(BLOCK) void seed_kernel(
    const float* __restrict__ points,
    const unsigned* __restrict__ histFC,
    const float4* __restrict__ fA, const float4* __restrict__ fB,
    const float4* __restrict__ fC,
    unsigned long long* __restrict__ best, unsigned* __restrict__ hint)
{
    const int t = blockIdx.x * BLOCK + threadIdx.x;   // 2*PTOT threads
    const int pid = t >> 1;
    const int s = t & 1;
    const float px = points[pid*3+0];
    const float py = points[pid*3+1];
    const float pz = points[pid*3+2];
    const unsigned code = morton12(px, py, pz);
    int w = (int)histFC[code] - 16;
    w = w < 0 ? 0 : (w > FTOT - 32 ? FTOT - 32 : w);

    unsigned long long pk = ~0ull;
    const int base = w + s * 16;
    for (int k = 0; k < 16; ++k) {
        const int i = base + k;
        const float4 A = fA[i], B = fB[i], C = fC[i];
        const float d = exec_pair(px, py, pz, A.x, A.y, A.z, B.x, B.y, B.z, C.x, C.y, C.z);
        const unsigned long long e =
            ((unsigned long long)__float_as_uint(d) << 32) | __float_as_uint(A.w);
        if (e < pk) pk = e;
    }
    const unsigned long long other = __shfl_xor(pk, 1, 64);
    if (other < pk) pk = other;
    if (s == 0) {
        best[pid] = pk;
        hint[pid] = __float_as_uint(sqrtf(__uint_as_float((unsigned)(pk >> 32))));
    }
}

// ---- phase 1: scan + emit ----
__global__ __launch_bounds__(BLOCK) void scan_emit_kernel(
    const uint4* __restrict__ sortP,
    const float4* __restrict__ fScan, const float* __restrict__ fBand,
    const float4* __restrict__ fBoxC, const float4* __restrict__ fBoxH,
    const float4* __restrict__ fA, const float4* __restrict__ fB,
    const float4* __restrict__ fC,
    const unsigned* __restrict__ hint,
    unsigned* __restrict__ list, unsigned* __restrict__ listCnt, unsigned CAP,
    unsigned long long* __restrict__ best)
{
    const int tid = threadIdx.x;
    const unsigned lane = (unsigned)(tid & 63);
    const uint4 sp = sortP[blockIdx.x * BLOCK + tid];
    const float px = __uint_as_float(sp.x);
    const float py = __uint_as_float(sp.y);
    const float pz = __uint_as_float(sp.z);
    const unsigned pid = sp.w;

    const float hS  = __uint_as_float(hint[pid]);
    const float thr = __fmaf_rn(hS, 1.005f, 1e-3f);

    const int fbase = (int)blockIdx.y * FCHUNK;

    for (int w0 = 0; w0 < FCHUNK; w0 += 64) {
        const int wb = fbase + w0;
        // --- plane-band scan: wave-uniform loads, per-lane 64-bit mask ---
        unsigned long long mask = 0ull;
#pragma unroll 8
        for (int k = 0; k < 64; ++k) {
            const float4 sc = fScan[wb + k];
            const float pd = __fmaf_rn(sc.x, px, __fmaf_rn(sc.y, py, __fmaf_rn(sc.z, pz, sc.w)));
            mask |= (fabsf(pd) <= thr + fBand[wb + k]) ? (1ull << k) : 0ull;
        }

        // --- box filter + wave-aggregated emission ---
        while (__ballot(mask != 0ull)) {
            bool cand = false;
            int fi = 0;
            if (mask != 0ull) {
                const int k = (int)__builtin_ctzll(mask);
                mask &= mask - 1ull;
                fi = wb + k;
                const float4 BC = fBoxC[fi];
                const float4 BH = fBoxH[fi];
                const float ex = fmaxf(fabsf(px - BC.x) - BC.w, 0.0f);
                const float ey = fmaxf(fabsf(py - BC.y) - BH.x, 0.0f);
                const float ez = fmaxf(fabsf(pz - BC.z) - BH.y, 0.0f);
                const float lb2 = __fmaf_rn(ex, ex, __fmaf_rn(ey, ey, ez * ez));
                const float rhs = thr + BH.z;       // inf-safe
                cand = !(lb2 > rhs * rhs);          // NaN -> candidate
            }
            const unsigned long long cb = __ballot(cand);
            if (cb) {
                const int n = __popcll(cb);
                const int leader = (int)__builtin_ctzll(cb);
                unsigned basei = 0;
                if ((int)lane == leader) basei = atomicAdd(listCnt, (unsigned)n);
                basei = __shfl(basei, leader, 64);
                if (cand) {
                    const unsigned off = (unsigned)__popcll(cb & ((1ull << lane) - 1ull));
                    const unsigned slot = basei + off;
                    if (slot < CAP) {
                        list[slot] = (pid << 16) | (unsigned)fi;
                    } else {
                        // overflow: inline exact exec (rare; always correct)
                        const float4 A = fA[fi], B = fB[fi], C = fC[fi];
                        const float d = exec_pair(px, py, pz,
                            A.x, A.y, A.z, B.x, B.y, B.z, C.x, C.y, C.z);
                        const unsigned long long pk =
                            ((unsigned long long)__float_as_uint(d) << 32) | __float_as_uint(A.w);
                        atomicMin(&best[pid], pk);
                    }
                }
            }
        }
    }
}

// ---- phase 2: parallel exec of the worklist ----
__global__ __launch_bounds__(BLOCK) void exec_kernel(
    const unsigned* __restrict__ list, const unsigned* __restrict__ listCnt,
    unsigned CAP,
    const float* __restrict__ points,
    const float4* __restrict__ fA, const float4* __restrict__ fB,
    const float4* __restrict__ fC,
    unsigned long long* __restrict__ best)
{
    unsigned tot = *listCnt;
    if (tot > CAP) tot = CAP;
    for (unsigned i = blockIdx.x * BLOCK + threadIdx.x; i < tot;
         i += gridDim.x * BLOCK) {
        const unsigned e = list[i];
        const unsigned pid = e >> 16;
        const int fi = (int)(e & 0xFFFFu);
        const float px = points[pid*3+0];
        const float py = points[pid*3+1];
        const float pz = points[pid*3+2];
        const float4 A = fA[fi], B = fB[fi], C = fC[fi];
        const float d = exec_pair(px, py, pz, A.x, A.y, A.z, B.x, B.y, B.z, C.x, C.y, C.z);
        const unsigned long long pk =
            ((unsigned long long)__float_as_uint(d) << 32) | __float_as_uint(A.w);
        atomicMin(&best[pid], pk);
    }
}

__global__ __launch_bounds__(BLOCK) void sdf_final_kernel(
    const unsigned long long* __restrict__ best, float* __restrict__ out)
{
    __shared__ float wsum[BLOCK / 64];
    const int p = blockIdx.x * BLOCK + threadIdx.x;
    const unsigned long long v = best[p];
    const float d = __uint_as_float((unsigned)(v >> 32));
    const int idx = (int)(unsigned)(v & 0xffffffffull);
    out[1 + p] = d;
    out[1 + PTOT + p] = (float)idx;

    float s = d;
    for (int off = 32; off > 0; off >>= 1) s += __shfl_down(s, off, 64);
    const int lane = threadIdx.x & 63;
    const int w = threadIdx.x >> 6;
    if (lane == 0) wsum[w] = s;
    __syncthreads();
    if (threadIdx.x == 0) {
        float tsum = 0.0f;
        for (int i = 0; i < BLOCK / 64; ++i) tsum += wsum[i];
        atomicAdd(&out[0], tsum);
    }
}

extern "C" void kernel_launch(void* const* d_in, const int* in_sizes, int n_in,
                              void* d_out, int out_size, void* d_ws, size_t ws_size,
                              hipStream_t stream) {
    const float* verts  = (const float*)d_in[0];
    const int*   faces  = (const int*)d_in[1];
    const float* points = (const float*)d_in[2];
    float* out = (float*)d_out;

    char* ws = (char*)d_ws;
    unsigned long long* best = (unsigned long long*)(ws + WS_BEST);
    uint4*    sortP   = (uint4*)(ws + WS_SORTP);
    unsigned* histP   = (unsigned*)(ws + WS_HISTP);
    unsigned* histF   = (unsigned*)(ws + WS_HISTF);
    unsigned* listCnt = (unsigned*)(ws + WS_LISTCNT);
    unsigned* histFC  = (unsigned*)(ws + WS_HISTFC);
    unsigned* hint    = (unsigned*)(ws + WS_HINT);
    float4* fA    = (float4*)(ws + WS_FA);
    float4* fB    = (float4*)(ws + WS_FB);
    float4* fC    = (float4*)(ws + WS_FC);
    float4* fScan = (float4*)(ws + WS_FSCAN);
    float*  fBand = (float*)(ws + WS_FBAND);
    float4* fBoxC = (float4*)(ws + WS_FBOXC);
    float4* fBoxH = (float4*)(ws + WS_FBOXH);
    unsigned* list = (unsigned*)(ws + WS_LIST);

    unsigned CAP = 0;
    if (ws_size > (size_t)WS_LIST + 16)
        CAP = (unsigned)(((ws_size - WS_LIST) / 4) - 1);
    if (CAP > (1u << 23)) CAP = (1u << 23);   // 8M entries max

    hipMemsetAsync(histP, 0, (size_t)ZERO_BYTES, stream);  // histP+histF+listCnt
    hipMemsetAsync(out, 0, sizeof(float), stream);

    hist_kernel<<<128, BLOCK, 0, stream>>>(verts, faces, points, histP, histF);
    scan_kernel<<<2, 256, 0, stream>>>(histP, histF, histFC);
    scatter_build_kernel<<<128, BLOCK, 0, stream>>>(verts, faces, points,
        histP, histF, sortP, fA, fB, fC, fScan, fBand, fBoxC, fBoxH);

    seed_kernel<<<2 * PTOT / BLOCK, BLOCK, 0, stream>>>(points, histFC,
        fA, fB, fC, best, hint);

    dim3 grid(PTOT / BLOCK, NCH);
    scan_emit_kernel<<<grid, BLOCK, 0, stream>>>(sortP,
        fScan, fBand, fBoxC, fBoxH, fA, fB, fC, hint, list, listCnt, CAP, best);

    exec_kernel<<<1024, BLOCK, 0, stream>>>(list, listCnt, CAP,
        points, fA, fB, fC, best);

    sdf_final_kernel<<<PTOT / BLOCK, BLOCK, 0, stream>>>(best, out);
}

// Round 13
// 309.354 us; speedup vs baseline: 9.6167x; 9.6167x over previous
//
#include <hip/hip_runtime.h>
#include <math.h>

// MeshSDFLoss: P=16384 points vs F=16384 triangles, min sqdist + argmin + loss.
// Outputs (flat float32): [0]=loss, [1..P]=dist, [1+P..1+2P]=assoc (as float).
//
// R13: seed -> fused scan+filter (all-scalar face metadata) -> block-local LDS
// queue -> block-cooperative bit-exact exec.
//  - Phase 0 (seed): 32 exact execs/point from the Morton face window ->
//    best[p], hint[p] (plain stores).
//  - Main: fixed thr = hint*1.005+1e-3 per point. Per face (wave-uniform
//    scalar loads): plane-band (R7 kp certificate) AND AABB+J filter (R11
//    certificate). Survivors -> per-block LDS queue (ds atomicAdd; zero
//    global atomics in-loop). Window drain: 256 threads cooperatively exec
//    queue entries (bit-exact R2 chain), merge via LDS u64 atomicMin into
//    per-point sBest; one global atomicMin per (point, chunk) at kernel end.
//    Queue overflow -> inline exec (correctness never depends on capacity).
//  - Certificates: skip => ref_d > thr >= sqrt(final_best)*1.005+1e-3 =>
//    skipped face can never be or tie the argmin. Exempt faces (noise-
//    dominated denominators): band=1e30, J=1e30 -> always executed.
//  - Tie-break: packed (distbits<<32)|origIdx u64 min == np.argmin first-idx.

#define PTOT 16384
#define FTOT 16384
#define NBINS 4096
#define BLOCK 256
#define NCH 32
#define FCHUNK (FTOT / NCH)   // 512 faces per chunk, 8 windows of 64
#define QCAP 2048             // per-block LDS queue entries

// ws layout (bytes)
#define WS_BEST    0           // u64[16384]            -> 131072
#define WS_SORTP   131072      // uint4[16384]          -> 393216
#define WS_HISTP   393216      // u32[4096]             -> 409600   (zeroed)
#define WS_HISTF   409600      // u32[4096]             -> 425984   (zeroed)
#define WS_HISTFC  425984      // u32[4096]             -> 442368
#define WS_HINT    442368      // u32[16384]            -> 507904
#define WS_FA      507904      // float4[16384] {a, origIdxBits}
#define WS_FB      770048      // float4[16384]
#define WS_FC      1032192     // float4[16384]
#define WS_FSCAN   1294336     // float4[16384] {nh, md0}
#define WS_FBAND   1556480     // float[16384]  {kp band}
#define WS_FBOXC   1622016     // float4[16384] {box center, hx}
#define WS_FBOXH   1884160     // float4[16384] {hy, hz, J, 0}
#define ZERO_BYTES (16384 + 16384)   // histP + histF

__device__ __forceinline__ unsigned morton12(float x, float y, float z) {
    int ix = (int)(x * 16.0f); ix = ix < 0 ? 0 : (ix > 15 ? 15 : ix);
    int iy = (int)(y * 16.0f); iy = iy < 0 ? 0 : (iy > 15 ? 15 : iy);
    int iz = (int)(z * 16.0f); iz = iz < 0 ? 0 : (iz > 15 ? 15 : iz);
    unsigned code = 0;
#pragma unroll
    for (int k = 0; k < 4; ++k) {
        code |= (((unsigned)(ix >> k) & 1u) << (3 * k + 2))
              | (((unsigned)(iy >> k) & 1u) << (3 * k + 1))
              | (((unsigned)(iz >> k) & 1u) << (3 * k + 0));
    }
    return code;
}

// Bit-exact point-triangle squared distance (reference-identical rounding).
__device__ __forceinline__ float exec_pair(
    float px, float py, float pz,
    float ax, float ay, float az,
    float bx, float by, float bz,
    float cx, float cy, float cz)
{
#pragma clang fp contract(off)
    const float abx = __fsub_rn(bx, ax), aby = __fsub_rn(by, ay), abz = __fsub_rn(bz, az);
    const float acx = __fsub_rn(cx, ax), acy = __fsub_rn(cy, ay), acz = __fsub_rn(cz, az);
    const float cbx = __fsub_rn(cx, bx), cby = __fsub_rn(cy, by), cbz = __fsub_rn(cz, bz);

    const float apx = __fsub_rn(px, ax), apy = __fsub_rn(py, ay), apz = __fsub_rn(pz, az);
    const float d1 = __fadd_rn(__fadd_rn(__fmul_rn(abx, apx), __fmul_rn(aby, apy)), __fmul_rn(abz, apz));
    const float d2 = __fadd_rn(__fadd_rn(__fmul_rn(acx, apx), __fmul_rn(acy, apy)), __fmul_rn(acz, apz));
    const float bpx = __fsub_rn(px, bx), bpy = __fsub_rn(py, by), bpz = __fsub_rn(pz, bz);
    const float d3 = __fadd_rn(__fadd_rn(__fmul_rn(abx, bpx), __fmul_rn(aby, bpy)), __fmul_rn(abz, bpz));
    const float d4 = __fadd_rn(__fadd_rn(__fmul_rn(acx, bpx), __fmul_rn(acy, bpy)), __fmul_rn(acz, bpz));
    const float cpx = __fsub_rn(px, cx), cpy = __fsub_rn(py, cy), cpz = __fsub_rn(pz, cz);
    const float d5 = __fadd_rn(__fadd_rn(__fmul_rn(abx, cpx), __fmul_rn(aby, cpy)), __fmul_rn(abz, cpz));
    const float d6 = __fadd_rn(__fadd_rn(__fmul_rn(acx, cpx), __fmul_rn(acy, cpy)), __fmul_rn(acz, cpz));

    const float vc_ = __fsub_rn(__fmul_rn(d1, d4), __fmul_rn(d3, d2));
    const float vb_ = __fsub_rn(__fmul_rn(d5, d2), __fmul_rn(d1, d6));
    const float va_ = __fsub_rn(__fmul_rn(d3, d6), __fmul_rn(d5, d4));

    const float den_ab = __fsub_rn(d1, d3);
    const float den_ac = __fsub_rn(d2, d6);
    const float t43    = __fsub_rn(d4, d3);
    const float t56    = __fsub_rn(d5, d6);
    const float den_bc = __fadd_rn(t43, t56);
    const float den_in = __fadd_rn(__fadd_rn(va_, vb_), vc_);

    const bool f_a  = (d1 <= 0.0f) && (d2 <= 0.0f);
    const bool f_b  = (d3 >= 0.0f) && (d4 <= d3);
    const bool f_c  = (d6 >= 0.0f) && (d5 <= d6);
    const bool f_ab = (vc_ <= 0.0f) && (d1 >= 0.0f) && (d3 <= 0.0f);
    const bool f_ac = (vb_ <= 0.0f) && (d2 >= 0.0f) && (d6 <= 0.0f);
    const bool f_bc = (va_ <= 0.0f) && (t43 >= 0.0f) && (t56 >= 0.0f);
    const bool vert = f_a || f_b || f_c;
    const bool e_ab = f_ab && !vert;
    const bool e_ac = f_ac && !vert && !f_ab;
    const bool e_bc = f_bc && !vert && !f_ab && !f_ac;
    const bool inte = !vert && !f_ab && !f_ac && !f_bc;

    const float num  = e_ab ? d1 : (e_ac ? d2 : (e_bc ? t43 : 1.0f));
    const float denr = e_ab ? den_ab : (e_ac ? den_ac : (e_bc ? den_bc : den_in));
    const float den  = (denr != 0.0f) ? denr : 1.0f;
    const float t    = __fdiv_rn(num, den);

    const float v_in = __fmul_rn(vb_, t);
    const float w_in = __fmul_rn(vc_, t);

    const float s1 = vert ? 0.0f : (inte ? v_in : t);
    const float s2 = inte ? w_in : 0.0f;
    const bool  sel_b = (!f_a && f_b) || e_bc;
    const bool  sel_c = !f_a && !f_b && f_c;
    const float e1x = e_ac ? acx : (e_bc ? cbx : abx);
    const float e1y = e_ac ? acy : (e_bc ? cby : aby);
    const float e1z = e_ac ? acz : (e_bc ? cbz : abz);
    const float bsx = sel_b ? bx : (sel_c ? cx : ax);
    const float bsy = sel_b ? by : (sel_c ? cy : ay);
    const float bsz = sel_b ? bz : (sel_c ? cz : az);
    const float qx = __fadd_rn(__fadd_rn(bsx, __fmul_rn(e1x, s1)), __fmul_rn(acx, s2));
    const float qy = __fadd_rn(__fadd_rn(bsy, __fmul_rn(e1y, s1)), __fmul_rn(acy, s2));
    const float qz = __fadd_rn(__fadd_rn(bsz, __fmul_rn(e1z, s1)), __fmul_rn(acz, s2));

    const float dxx = __fsub_rn(px, qx), dyy = __fsub_rn(py, qy), dzz = __fsub_rn(pz, qz);
    return __fadd_rn(__fadd_rn(__fmul_rn(dxx, dxx), __fmul_rn(dyy, dyy)), __fmul_rn(dzz, dzz));
}

// ---- prep: histograms ----
__global__ __launch_bounds__(BLOCK) void hist_kernel(
    const float* __restrict__ verts, const int* __restrict__ faces,
    const float* __restrict__ points,
    unsigned* __restrict__ histP, unsigned* __restrict__ histF)
{
    const int b = blockIdx.x;
    if (b < 64) {
        const int p = b * BLOCK + threadIdx.x;
        atomicAdd(&histP[morton12(points[p*3], points[p*3+1], points[p*3+2])], 1u);
    } else {
        const int f = (b - 64) * BLOCK + threadIdx.x;
        const int i0 = faces[f*3+0], i1 = faces[f*3+1], i2 = faces[f*3+2];
        const float mx = (verts[i0*3+0] + verts[i1*3+0] + verts[i2*3+0]) * (1.0f/3.0f);
        const float my = (verts[i0*3+1] + verts[i1*3+1] + verts[i2*3+1]) * (1.0f/3.0f);
        const float mz = (verts[i0*3+2] + verts[i1*3+2] + verts[i2*3+2]) * (1.0f/3.0f);
        atomicAdd(&histF[morton12(mx, my, mz)], 1u);
    }
}

__global__ __launch_bounds__(256) void scan_kernel(
    unsigned* __restrict__ histP, unsigned* __restrict__ histF,
    unsigned* __restrict__ histFC)
{
    unsigned* h = (blockIdx.x == 0) ? histP : histF;
    __shared__ unsigned ps[256];
    const int t = threadIdx.x;
    unsigned local[16];
    unsigned run = 0;
#pragma unroll
    for (int i = 0; i < 16; ++i) { unsigned v = h[t*16+i]; local[i] = run; run += v; }
    ps[t] = run;
    __syncthreads();
    for (int off = 1; off < 256; off <<= 1) {
        unsigned v = (t >= off) ? ps[t - off] : 0u;
        __syncthreads();
        ps[t] += v;
        __syncthreads();
    }
    const unsigned base = (t == 0) ? 0u : ps[t-1];
#pragma unroll
    for (int i = 0; i < 16; ++i) {
        const unsigned off = base + local[i];
        h[t*16+i] = off;
        if (blockIdx.x == 1) histFC[t*16+i] = off;
    }
}

// ---- prep: scatter + build certified metadata (fp64) ----
__global__ __launch_bounds__(BLOCK) void scatter_build_kernel(
    const float* __restrict__ verts, const int* __restrict__ faces,
    const float* __restrict__ points,
    unsigned* __restrict__ histP, unsigned* __restrict__ histF,
    uint4* __restrict__ sortP,
    float4* __restrict__ fA, float4* __restrict__ fB, float4* __restrict__ fC,
    float4* __restrict__ fScan, float* __restrict__ fBand,
    float4* __restrict__ fBoxC, float4* __restrict__ fBoxH)
{
    const int b = blockIdx.x;
    if (b < 64) {
        const int p = b * BLOCK + threadIdx.x;
        const float x = points[p*3], y = points[p*3+1], z = points[p*3+2];
        const unsigned pos = atomicAdd(&histP[morton12(x, y, z)], 1u);
        sortP[pos] = make_uint4(__float_as_uint(x), __float_as_uint(y),
                                __float_as_uint(z), (unsigned)p);
        return;
    }
    const int f = (b - 64) * BLOCK + threadIdx.x;
    const int i0 = faces[f*3+0], i1 = faces[f*3+1], i2 = faces[f*3+2];
    const float ax = verts[i0*3+0], ay = verts[i0*3+1], az = verts[i0*3+2];
    const float bx = verts[i1*3+0], by = verts[i1*3+1], bz = verts[i1*3+2];
    const float cx = verts[i2*3+0], cy = verts[i2*3+1], cz = verts[i2*3+2];
    const float mx = (ax+bx+cx) * (1.0f/3.0f);
    const float my = (ay+by+cy) * (1.0f/3.0f);
    const float mz = (az+bz+cz) * (1.0f/3.0f);
    const unsigned pos = atomicAdd(&histF[morton12(mx, my, mz)], 1u);

    fA[pos] = make_float4(ax, ay, az, __uint_as_float((unsigned)f));
    fB[pos] = make_float4(bx, by, bz, 0.0f);
    fC[pos] = make_float4(cx, cy, cz, 0.0f);

    const double abx = (double)bx-ax, aby = (double)by-ay, abz = (double)bz-az;
    const double acx = (double)cx-ax, acy = (double)cy-ay, acz = (double)cz-az;
    const double cbx = (double)cx-bx, cby = (double)cy-by, cbz = (double)cz-bz;
    const double nx = aby*acz - abz*acy;
    const double ny = abz*acx - abx*acz;
    const double nz = abx*acy - aby*acx;
    const double nn = nx*nx + ny*ny + nz*nz;
    const double e1 = sqrt(abx*abx + aby*aby + abz*abz);
    const double e2 = sqrt(acx*acx + acy*acy + acz*acz);
    const double e3 = sqrt(cbx*cbx + cby*cby + cbz*cbz);
    const double maxe = fmax(e1, fmax(e2, e3));
    const double mine = fmin(e1, fmin(e2, e3));
    const double mine2 = mine * mine;
    const double maxe2 = maxe * maxe;
    const double maxe3 = maxe2 * maxe;

    const bool exempt = !(nn > 1e-5 * maxe2) || !(mine2 > 5e-6 * maxe);

    float4 sc;
    float band, J;
    if (!exempt) {
        const double rin = 1.0 / sqrt(nn);
        sc.x = (float)(nx * rin);
        sc.y = (float)(ny * rin);
        sc.z = (float)(nz * rin);
        sc.w = (float)(-(nx*rin*ax + ny*rin*ay + nz*rin*az));
        band = (float)fmin(1e4, 3e-5 * maxe3 / nn + 2e-5);
        J    = (float)fmin(1e4, 1.2 * (6e-5 * maxe3 / nn
                                     + 5e-5 * maxe2 / mine2
                                     + 2.6e-6 * maxe / mine
                                     + 3.2e-3));
    } else {
        sc = make_float4(0.0f, 0.0f, 0.0f, 0.0f);  // pd = 0 -> always in band
        band = 1e30f;
        J    = 1e30f;                               // never box-skipped
    }
    fScan[pos] = sc;
    fBand[pos] = band;

    const double mnx = fmin((double)ax, fmin((double)bx, (double)cx));
    const double mxx = fmax((double)ax, fmax((double)bx, (double)cx));
    const double mny = fmin((double)ay, fmin((double)by, (double)cy));
    const double mxy = fmax((double)ay, fmax((double)by, (double)cy));
    const double mnz = fmin((double)az, fmin((double)bz, (double)cz));
    const double mxz = fmax((double)az, fmax((double)bz, (double)cz));
    const float ccx = (float)((mnx + mxx) * 0.5);
    const float ccy = (float)((mny + mxy) * 0.5);
    const float ccz = (float)((mnz + mxz) * 0.5);
    const float hx = (float)((mxx - mnx) * 0.5 * 1.0002 + 2e-5);
    const float hy = (float)((mxy - mny) * 0.5 * 1.0002 + 2e-5);
    const float hz = (float)((mxz - mnz) * 0.5 * 1.0002 + 2e-5);
    fBoxC[pos] = make_float4(ccx, ccy, ccz, hx);
    fBoxH[pos] = make_float4(hy, hz, J, 0.0f);
}

// ---- phase 0: 32 exact seeds/point, plain-store best+hint ----
__global__ __launch_bounds__(BLOCK) void seed_kernel(
    const float* __restrict__ points,
    const unsigned* __restrict__ histFC,
    const float4* __restrict__ fA, const float4* __restrict__ fB,
    const float4* __restrict__ fC,
    unsigned long long* __restrict__ best, unsigned* __restrict__ hint)
{
    const int t = blockIdx.x * BLOCK + threadIdx.x;   // 2*PTOT threads
    const int pid = t >> 1;
    const int s = t & 1;
    const float px = points[pid*3+0];
    const float py = points[pid*3+1];
    const float pz = points[pid*3+2];
    const unsigned code = morton12(px, py, pz);
    int w = (int)histFC[code] - 16;
    w = w < 0 ? 0 : (w > FTOT - 32 ? FTOT - 32 : w);

    unsigned long long pk = ~0ull;
    const int base = w + s * 16;
    for (int k = 0; k < 16; ++k) {
        const int i = base + k;
        const float4 A = fA[i], B = fB[i], C = fC[i];
        const float d = exec_pair(px, py, pz, A.x, A.y, A.z, B.x, B.y, B.z, C.x, C.y, C.z);
        const unsigned long long e =
            ((unsigned long long)__float_as_uint(d) << 32) | __float_as_uint(A.w);
        if (e < pk) pk = e;
    }
    const unsigned long long other = __shfl_xor(pk, 1, 64);
    if (other < pk) pk = other;
    if (s == 0) {
        best[pid] = pk;
        hint[pid] = __float_as_uint(sqrtf(__uint_as_float((unsigned)(pk >> 32))));
    }
}

// ---- main: fused scan+filter -> LDS queue -> cooperative exec ----
__global__ __launch_bounds__(BLOCK) void sdf_main_kernel(
    const uint4* __restrict__ sortP,
    const float4* __restrict__ fScan, const float* __restrict__ fBand,
    const float4* __restrict__ fBoxC, const float4* __restrict__ fBoxH,
    const float4* __restrict__ fA, const float4* __restrict__ fB,
    const float4* __restrict__ fC,
    const unsigned* __restrict__ hint,
    unsigned long long* __restrict__ best)
{
    __shared__ float sPx[BLOCK], sPy[BLOCK], sPz[BLOCK];
    __shared__ unsigned sPid[BLOCK];
    __shared__ unsigned long long sBest[BLOCK];
    __shared__ unsigned sQ[QCAP];
    __shared__ unsigned sQcnt;

    const int tid = threadIdx.x;
    const uint4 sp = sortP[blockIdx.x * BLOCK + tid];
    const float px = __uint_as_float(sp.x);
    const float py = __uint_as_float(sp.y);
    const float pz = __uint_as_float(sp.z);
    const unsigned pid = sp.w;

    sPx[tid] = px; sPy[tid] = py; sPz[tid] = pz; sPid[tid] = pid;
    sBest[tid] = best[pid];   // seeded by seed_kernel (plain store, prior kernel)
    if (tid == 0) sQcnt = 0;
    const float thr = __fmaf_rn(__uint_as_float(hint[pid]), 1.005f, 1e-3f);
    __syncthreads();

    const int fbase = (int)blockIdx.y * FCHUNK;

    for (int w0 = 0; w0 < FCHUNK; w0 += 64) {
        const int wb = fbase + w0;

        // --- fused scan: plane-band AND box filter, all-scalar face data ---
#pragma unroll 4
        for (int k = 0; k < 64; ++k) {
            const float4 sc = fScan[wb + k];
            const float band = fBand[wb + k];
            const float4 BC = fBoxC[wb + k];
            const float4 BH = fBoxH[wb + k];
            const float pd = __fmaf_rn(sc.x, px, __fmaf_rn(sc.y, py, __fmaf_rn(sc.z, pz, sc.w)));
            const bool inband = !(fabsf(pd) > thr + band);          // NaN-safe
            const float ex = fmaxf(fabsf(px - BC.x) - BC.w, 0.0f);
            const float ey = fmaxf(fabsf(py - BC.y) - BH.x, 0.0f);
            const float ez = fmaxf(fabsf(pz - BC.z) - BH.y, 0.0f);
            const float lb2 = __fmaf_rn(ex, ex, __fmaf_rn(ey, ey, ez * ez));
            const float rhs = thr + BH.z;                            // inf-safe
            const bool inbox = !(lb2 > rhs * rhs);                   // NaN-safe
            if (inband && inbox) {
                const unsigned idx = atomicAdd(&sQcnt, 1u);          // LDS atomic
                if (idx < QCAP) {
                    sQ[idx] = ((unsigned)tid << 16) | (unsigned)(wb + k);
                } else {
                    // overflow: inline exact exec (rare; always correct)
                    const int fi = wb + k;
                    const float4 A = fA[fi], B = fB[fi], C = fC[fi];
                    const float d = exec_pair(px, py, pz,
                        A.x, A.y, A.z, B.x, B.y, B.z, C.x, C.y, C.z);
                    const unsigned long long pk =
                        ((unsigned long long)__float_as_uint(d) << 32) | __float_as_uint(A.w);
                    atomicMin(&sBest[tid], pk);
                }
            }
        }

        // --- cooperative drain (load-balanced across the block) ---
        __syncthreads();
        const unsigned n = (sQcnt < QCAP) ? sQcnt : QCAP;
        for (unsigned i = (unsigned)tid; i < n; i += BLOCK) {
            const unsigned e = sQ[i];
            const unsigned et = e >> 16;
            const int fi = (int)(e & 0xFFFFu);
            const float qx = sPx[et], qy = sPy[et], qz = sPz[et];
            const float4 A = fA[fi], B = fB[fi], C = fC[fi];
            const float d = exec_pair(qx, qy, qz,
                A.x, A.y, A.z, B.x, B.y, B.z, C.x, C.y, C.z);
            const unsigned long long pk =
                ((unsigned long long)__float_as_uint(d) << 32) | __float_as_uint(A.w);
            atomicMin(&sBest[et], pk);     // LDS u64 atomic
        }
        __syncthreads();
        if (tid == 0) sQcnt = 0;
        __syncthreads();
    }

    // one global publish per (point, chunk)
    atomicMin(&best[pid], sBest[tid]);
}

__global__ __launch_bounds__(BLOCK) void sdf_final_kernel(
    const unsigned long long* __restrict__ best, float* __restrict__ out)
{
    __shared__ float wsum[BLOCK / 64];
    const int p = blockIdx.x * BLOCK + threadIdx.x;
    const unsigned long long v = best[p];
    const float d = __uint_as_float((unsigned)(v >> 32));
    const int idx = (int)(unsigned)(v & 0xffffffffull);
    out[1 + p] = d;
    out[1 + PTOT + p] = (float)idx;

    float s = d;
    for (int off = 32; off > 0; off >>= 1) s += __shfl_down(s, off, 64);
    const int lane = threadIdx.x & 63;
    const int w = threadIdx.x >> 6;
    if (lane == 0) wsum[w] = s;
    __syncthreads();
    if (threadIdx.x == 0) {
        float tsum = 0.0f;
        for (int i = 0; i < BLOCK / 64; ++i) tsum += wsum[i];
        atomicAdd(&out[0], tsum);
    }
}

extern "C" void kernel_launch(void* const* d_in, const int* in_sizes, int n_in,
                              void* d_out, int out_size, void* d_ws, size_t ws_size,
                              hipStream_t stream) {
    const float* verts  = (const float*)d_in[0];
    const int*   faces  = (const int*)d_in[1];
    const float* points = (const float*)d_in[2];
    float* out = (float*)d_out;

    char* ws = (char*)d_ws;
    unsigned long long* best = (unsigned long long*)(ws + WS_BEST);
    uint4*    sortP   = (uint4*)(ws + WS_SORTP);
    unsigned* histP   = (unsigned*)(ws + WS_HISTP);
    unsigned* histF   = (unsigned*)(ws + WS_HISTF);
    unsigned* histFC  = (unsigned*)(ws + WS_HISTFC);
    unsigned* hint    = (unsigned*)(ws + WS_HINT);
    float4* fA    = (float4*)(ws + WS_FA);
    float4* fB    = (float4*)(ws + WS_FB);
    float4* fC    = (float4*)(ws + WS_FC);
    float4* fScan = (float4*)(ws + WS_FSCAN);
    float*  fBand = (float*)(ws + WS_FBAND);
    float4* fBoxC = (float4*)(ws + WS_FBOXC);
    float4* fBoxH = (float4*)(ws + WS_FBOXH);

    hipMemsetAsync(histP, 0, (size_t)ZERO_BYTES, stream);  // histP + histF
    hipMemsetAsync(out, 0, sizeof(float), stream);

    hist_kernel<<<128, BLOCK, 0, stream>>>(verts, faces, points, histP, histF);
    scan_kernel<<<2, 256, 0, stream>>>(histP, histF, histFC);
    scatter_build_kernel<<<128, BLOCK, 0, stream>>>(verts, faces, points,
        histP, histF, sortP, fA, fB, fC, fScan, fBand, fBoxC, fBoxH);

    seed_kernel<<<2 * PTOT / BLOCK, BLOCK, 0, stream>>>(points, histFC,
        fA, fB, fC, best, hint);

    dim3 grid(PTOT / BLOCK, NCH);
    sdf_main_kernel<<<grid, BLOCK, 0, stream>>>(sortP,
        fScan, fBand, fBoxC, fBoxH, fA, fB, fC, hint, best);

    sdf_final_kernel<<<PTOT / BLOCK, BLOCK, 0, stream>>>(best, out);
}